// Round 2
// baseline (68.103 us; speedup 1.0000x reference)
//
#include <hip/hip_runtime.h>

// Quanvolution: 8112 independent 9-qubit statevector circuits.
// Algebra (HW-verified by round-1 pass, then relabeled):
//  - RX embed + layer-0 RX fuse: RX(p_i + w0_i); initial state is a product state.
//  - CNOT rings are GF(2) basis permutations -> never move data; relabel indices.
//    Round-1 verified butterfly masks m_q = {3,6,12,24,48,0x60,0xC0,0x180,0x103},
//    measurement rows r_f = {0x154,0x1FD,0x1FA,0x1F5}.
//  - NEW: extra lane-bit relabel L (i_low = L(j_low), j_low = lane ^ (lane<<1)):
//    maps lane masks {3,6,12,24,48,32,3} -> {1,2,4,8,16,32,1} (one 32-crossing
//    pass instead of two). Measurement masks transform to
//    RL = ((r^(r>>1))&0x1F)|(r&0x20) = {0x1E,0x23,0x27,0x2F}, RH = r>>6 = {5,7,7,7}.
//    Verified on probe cases q1-embed, w1[0], w1[5], w1[8] against round-1 algebra.
// Layout: 8 complex amps/lane in VGPRs, one wave per (pixel,channel) circuit,
// block = 192 = 3 waves = 3 channels of one pixel; channel mean via 48 B LDS.
// __launch_bounds__(192,8): force <=64 VGPR so all ~8112 waves are co-resident
// (round-1 version held scratch arrays -> ~2x occupancy loss).

static constexpr int CH = 3;
static constexpr int HOUT = 26;
static constexpr int WOUT = 26;

__device__ __forceinline__ float shflx(float v, int m) {
  return __shfl_xor(v, m, 64);
}

__global__ __launch_bounds__(192, 8) void quanv_kernel(
    const float* __restrict__ x,   // (4,3,28,28) f32
    const float* __restrict__ w,   // (2,9) f32
    float* __restrict__ out)       // (4,4,26,26) f32
{
  __shared__ float sm[CH * 4];

  const int pix  = blockIdx.x;
  const int b    = pix / (HOUT * WOUT);
  const int r    = pix % (HOUT * WOUT);
  const int oy   = r / WOUT;
  const int ox   = r % WOUT;
  const int ch   = threadIdx.x >> 6;
  const int lane = threadIdx.x & 63;
  const int jl   = (lane ^ (lane << 1)) & 63;   // j_low under lane relabel

  const float* xp = x + ((b * CH + ch) * 28 + oy) * 28 + ox;

  // ---- init: fold qubits 0..5 into the scalar product immediately ----
  float plo = 1.f;
#pragma unroll
  for (int q = 0; q < 6; ++q) {
    const float p  = xp[(q / 3) * 28 + (q % 3)];
    const float th = 0.5f * (p + w[q]);
    const float c = __cosf(th), s = __sinf(th);
    plo *= ((jl >> q) & 1) ? s : c;
  }
  float c6, s6, c7, s7, c8, s8;
  { const float th = 0.5f * (xp[2 * 28 + 0] + w[6]); c6 = __cosf(th); s6 = __sinf(th); }
  { const float th = 0.5f * (xp[2 * 28 + 1] + w[7]); c7 = __cosf(th); s7 = __sinf(th); }
  { const float th = 0.5f * (xp[2 * 28 + 2] + w[8]); c8 = __cosf(th); s8 = __sinf(th); }

  const int pclo = __popc(jl);
  float tr[8], ti[8];
#pragma unroll
  for (int k = 0; k < 8; ++k) {
    const float a = plo * ((k & 1) ? s6 : c6)
                        * ((k & 2) ? s7 : c7)
                        * ((k & 4) ? s8 : c8);
    const int pc = (pclo + __popc(k)) & 3;            // phase (-i)^pc
    tr[k] = (pc == 0) ? a : ((pc == 2) ? -a : 0.f);
    ti[k] = (pc == 3) ? a : ((pc == 1) ? -a : 0.f);
  }

  // ---- layer-1 passes, q=0..4: pure lane-xor masks 1,2,4,8,16 (in-place) ----
#pragma unroll
  for (int q = 0; q < 5; ++q) {
    const float th = 0.5f * w[9 + q];
    const float c = __cosf(th), s = __sinf(th);
    const int Lm = 1 << q;
#pragma unroll
    for (int k = 0; k < 8; ++k) {
      const float vr = shflx(tr[k], Lm);
      const float vi = shflx(ti[k], Lm);
      tr[k] = c * tr[k] + s * vi;
      ti[k] = c * ti[k] - s * vr;
    }
  }
  // ---- q=5: lane 32 + reg 1 ----
  {
    const float th = 0.5f * w[14];
    const float c = __cosf(th), s = __sinf(th);
#pragma unroll
    for (int k = 0; k < 8; k += 2) {
      const int p = k + 1;
      const float ar = shflx(tr[p], 32), ai = shflx(ti[p], 32);
      const float br = shflx(tr[k], 32), bi = shflx(ti[k], 32);
      tr[k] = c * tr[k] + s * ai;  ti[k] = c * ti[k] - s * ar;
      tr[p] = c * tr[p] + s * bi;  ti[p] = c * ti[p] - s * br;
    }
  }
  // ---- q=6: reg 3 ; q=7: reg 6 (register-local pairs) ----
#pragma unroll
  for (int qq = 0; qq < 2; ++qq) {
    const int K = qq ? 6 : 3;
    const float th = 0.5f * w[15 + qq];
    const float c = __cosf(th), s = __sinf(th);
#pragma unroll
    for (int k = 0; k < 8; ++k) {
      const int p = k ^ K;
      if (k < p) {
        const float ar = tr[p], ai = ti[p];
        const float br = tr[k], bi = ti[k];
        tr[k] = c * br + s * ai;  ti[k] = c * bi - s * ar;
        tr[p] = c * ar + s * bi;  ti[p] = c * ai - s * br;
      }
    }
  }
  // ---- q=8: lane 1 + reg 4 ----
  {
    const float th = 0.5f * w[17];
    const float c = __cosf(th), s = __sinf(th);
#pragma unroll
    for (int k = 0; k < 4; ++k) {
      const int p = k + 4;
      const float ar = shflx(tr[p], 1), ai = shflx(ti[p], 1);
      const float br = shflx(tr[k], 1), bi = shflx(ti[k], 1);
      tr[k] = c * tr[k] + s * ai;  ti[k] = c * ti[k] - s * ar;
      tr[p] = c * tr[p] + s * bi;  ti[p] = c * ti[p] - s * br;
    }
  }

  // ---- probabilities in place, then 4 filter expectations ----
#pragma unroll
  for (int k = 0; k < 8; ++k) tr[k] = tr[k] * tr[k] + ti[k] * ti[k];

  constexpr int RL[4] = {0x1E, 0x23, 0x27, 0x2F};
  constexpr int RH[4] = {5, 7, 7, 7};
  float z[4];
#pragma unroll
  for (int f = 0; f < 4; ++f) {
    float acc = 0.f;
#pragma unroll
    for (int k = 0; k < 8; ++k)
      acc += (__popc(RH[f] & k) & 1) ? -tr[k] : tr[k];
    z[f] = (__popc(RL[f] & lane) & 1) ? -acc : acc;
  }

#pragma unroll
  for (int m = 1; m < 64; m <<= 1)
#pragma unroll
    for (int f = 0; f < 4; ++f) z[f] += shflx(z[f], m);

  if (lane == 0) {
#pragma unroll
    for (int f = 0; f < 4; ++f) sm[ch * 4 + f] = z[f];
  }
  __syncthreads();

  if (threadIdx.x < 4) {
    const int f = threadIdx.x;
    out[((b * 4 + f) * HOUT + oy) * WOUT + ox] =
        (sm[f] + sm[4 + f] + sm[8 + f]) * (1.f / 3.f);
  }
}

extern "C" void kernel_launch(void* const* d_in, const int* in_sizes, int n_in,
                              void* d_out, int out_size, void* d_ws, size_t ws_size,
                              hipStream_t stream) {
  const float* x = (const float*)d_in[0];
  const float* w = (const float*)d_in[1];
  float* out = (float*)d_out;
  dim3 grid(4 * HOUT * WOUT);    // 2704 pixel blocks
  dim3 block(192);               // 3 waves = 3 channels
  hipLaunchKernelGGL(quanv_kernel, grid, block, 0, stream, x, w, out);
}

// Round 3
// 67.849 us; speedup vs baseline: 1.0037x; 1.0037x over previous
//
#include <hip/hip_runtime.h>

// Quanvolution: 8112 independent 9-qubit statevector circuits.
// Algebra identical to the round-2 HW-verified version (absmax 2.4e-4):
//  - RX embed + layer-0 fuse -> product state; CNOT rings -> GF(2) relabels.
//  - lane relabel jl = lane^(lane<<1): layer-1 masks q0..q4 = lane {1,2,4,8,16},
//    q5 = lane32+reg1, q6 = reg3, q7 = reg6, q8 = lane1+reg4.
//  - measurement RL = {0x1E,0x23,0x27,0x2F}, RH = {5,7,7,7}.
// Round-3 change: pack the 8 amps/lane as 4x float2 along reg-bit0 (state bit 6)
// so all butterflies/measurement/reduction emit v_pk_{mul,fma,add}_f32 —
// the kernel's dominant pipe is VALU (~700 cyc/wave), this halves it.
//  - q5's reg-xor-1 becomes a .yx swizzle; q6 = pair^1 + .yx; q7 = pair^3;
//    q8 = shfl(mask1) + pair^2. All RH masks odd -> z = acc.x - acc.y.
// DS-op count unchanged (~136/wave); trig unchanged (36 trans ops/wave).

static constexpr int CH = 3;
static constexpr int HOUT = 26;
static constexpr int WOUT = 26;

typedef float v2 __attribute__((ext_vector_type(2)));

__device__ __forceinline__ float shflx(float v, int m) {
  return __shfl_xor(v, m, 64);
}
__device__ __forceinline__ v2 shflx2(v2 v, int m) {
  v2 r;
  r.x = __shfl_xor(v.x, m, 64);
  r.y = __shfl_xor(v.y, m, 64);
  return r;
}

__global__ __launch_bounds__(192, 8) void quanv_kernel(
    const float* __restrict__ x,   // (4,3,28,28) f32
    const float* __restrict__ w,   // (2,9) f32
    float* __restrict__ out)       // (4,4,26,26) f32
{
  __shared__ float sm[CH * 4];

  const int pix  = blockIdx.x;
  const int b    = pix / (HOUT * WOUT);
  const int r    = pix % (HOUT * WOUT);
  const int oy   = r / WOUT;
  const int ox   = r % WOUT;
  const int ch   = threadIdx.x >> 6;
  const int lane = threadIdx.x & 63;
  const int jl   = (lane ^ (lane << 1)) & 63;   // relabeled low state bits

  const float* xp = x + ((b * CH + ch) * 28 + oy) * 28 + ox;

  // ---- init: fold state bits 0..5 into scalar product ----
  float plo = 1.f;
#pragma unroll
  for (int q = 0; q < 6; ++q) {
    const float p  = xp[(q / 3) * 28 + (q % 3)];
    const float th = 0.5f * (p + w[q]);
    plo *= ((jl >> q) & 1) ? __sinf(th) : __cosf(th);
  }
  float c6, s6, c7, s7, c8, s8;
  { const float th = 0.5f * (xp[2 * 28 + 0] + w[6]); c6 = __cosf(th); s6 = __sinf(th); }
  { const float th = 0.5f * (xp[2 * 28 + 1] + w[7]); c7 = __cosf(th); s7 = __sinf(th); }
  { const float th = 0.5f * (xp[2 * 28 + 2] + w[8]); c8 = __cosf(th); s8 = __sinf(th); }

  const int pclo = __popc(jl);
  // 8 amps/lane packed: pair a = (k>>1) in [0,4), component = k&1 (state bit 6)
  v2 tr[4], ti[4];
#pragma unroll
  for (int a = 0; a < 4; ++a) {
#pragma unroll
    for (int c = 0; c < 2; ++c) {
      const int k = (a << 1) | c;
      const float amp = plo * ((k & 1) ? s6 : c6)
                            * ((k & 2) ? s7 : c7)
                            * ((k & 4) ? s8 : c8);
      const int pc = (pclo + __popc(k)) & 3;     // phase (-i)^pc
      const float vr = (pc == 0) ? amp : ((pc == 2) ? -amp : 0.f);
      const float vi = (pc == 3) ? amp : ((pc == 1) ? -amp : 0.f);
      if (c == 0) { tr[a].x = vr; ti[a].x = vi; }
      else        { tr[a].y = vr; ti[a].y = vi; }
    }
  }

  // ---- q0..q4: pure lane-xor masks 1,2,4,8,16 ----
#pragma unroll
  for (int q = 0; q < 5; ++q) {
    const float th = 0.5f * w[9 + q];
    const float c = __cosf(th), s = __sinf(th);
    const int Lm = 1 << q;
#pragma unroll
    for (int a = 0; a < 4; ++a) {
      const v2 pr = shflx2(tr[a], Lm);
      const v2 pi = shflx2(ti[a], Lm);
      tr[a] = c * tr[a] + s * pi;
      ti[a] = c * ti[a] - s * pr;
    }
  }
  // ---- q5: lane 32 + component flip ----
  {
    const float th = 0.5f * w[14];
    const float c = __cosf(th), s = __sinf(th);
#pragma unroll
    for (int a = 0; a < 4; ++a) {
      const v2 pr = shflx2(tr[a], 32).yx;
      const v2 pi = shflx2(ti[a], 32).yx;
      tr[a] = c * tr[a] + s * pi;
      ti[a] = c * ti[a] - s * pr;
    }
  }
  // ---- q6: pair^1 + component flip (register-local) ----
  {
    const float th = 0.5f * w[15];
    const float c = __cosf(th), s = __sinf(th);
    v2 otr[4], oti[4];
#pragma unroll
    for (int a = 0; a < 4; ++a) { otr[a] = tr[a]; oti[a] = ti[a]; }
#pragma unroll
    for (int a = 0; a < 4; ++a) {
      tr[a] = c * otr[a] + s * oti[a ^ 1].yx;
      ti[a] = c * oti[a] - s * otr[a ^ 1].yx;
    }
  }
  // ---- q7: pair^3 (register-local) ----
  {
    const float th = 0.5f * w[16];
    const float c = __cosf(th), s = __sinf(th);
    v2 otr[4], oti[4];
#pragma unroll
    for (int a = 0; a < 4; ++a) { otr[a] = tr[a]; oti[a] = ti[a]; }
#pragma unroll
    for (int a = 0; a < 4; ++a) {
      tr[a] = c * otr[a] + s * oti[a ^ 3];
      ti[a] = c * oti[a] - s * otr[a ^ 3];
    }
  }
  // ---- q8: lane 1 + pair^2 ----
  {
    const float th = 0.5f * w[17];
    const float c = __cosf(th), s = __sinf(th);
    v2 pr[4], pi[4];
#pragma unroll
    for (int a = 0; a < 4; ++a) {
      pr[a] = shflx2(tr[a ^ 2], 1);
      pi[a] = shflx2(ti[a ^ 2], 1);
    }
#pragma unroll
    for (int a = 0; a < 4; ++a) {
      tr[a] = c * tr[a] + s * pi[a];
      ti[a] = c * ti[a] - s * pr[a];
    }
  }

  // ---- probabilities (packed, in place) ----
#pragma unroll
  for (int a = 0; a < 4; ++a) tr[a] = tr[a] * tr[a] + ti[a] * ti[a];

  // ---- filter expectations: RH = {5,7,7,7} (all odd), RL lane signs ----
  // array sign for pair a = popc((RH>>1)&a)&1 ; comp sign: y flips (RH&1==1)
  constexpr int RL[4] = {0x1E, 0x23, 0x27, 0x2F};
  constexpr int RHs[4] = {2, 3, 3, 3};   // RH>>1
  v2 zz[2];
#pragma unroll
  for (int f = 0; f < 4; ++f) {
    v2 acc = tr[0];
#pragma unroll
    for (int a = 1; a < 4; ++a)
      acc += (__popc(RHs[f] & a) & 1) ? -tr[a] : tr[a];
    float z = acc.x - acc.y;
    z = (__popc(RL[f] & lane) & 1) ? -z : z;
    if (f & 1) zz[f >> 1].y = z; else zz[f >> 1].x = z;
  }

  // ---- packed wave butterfly reduction ----
#pragma unroll
  for (int m = 1; m < 64; m <<= 1) {
    zz[0] += shflx2(zz[0], m);
    zz[1] += shflx2(zz[1], m);
  }
  if (lane == 0) {
    sm[ch * 4 + 0] = zz[0].x;
    sm[ch * 4 + 1] = zz[0].y;
    sm[ch * 4 + 2] = zz[1].x;
    sm[ch * 4 + 3] = zz[1].y;
  }
  __syncthreads();

  if (threadIdx.x < 4) {
    const int f = threadIdx.x;
    out[((b * 4 + f) * HOUT + oy) * WOUT + ox] =
        (sm[f] + sm[4 + f] + sm[8 + f]) * (1.f / 3.f);
  }
}

extern "C" void kernel_launch(void* const* d_in, const int* in_sizes, int n_in,
                              void* d_out, int out_size, void* d_ws, size_t ws_size,
                              hipStream_t stream) {
  const float* x = (const float*)d_in[0];
  const float* w = (const float*)d_in[1];
  float* out = (float*)d_out;
  dim3 grid(4 * HOUT * WOUT);    // 2704 pixel blocks
  dim3 block(192);               // 3 waves = 3 channels
  hipLaunchKernelGGL(quanv_kernel, grid, block, 0, stream, x, w, out);
}